// Round 1
// baseline (47911.841 us; speedup 1.0000x reference)
//
#include <hip/hip_runtime.h>
#include <math.h>

// Problem constants
// IN=1662, H=512, T=256, B=128, C=100
// Outputs: logits [128,100] (12800 floats) then attw [128,256,1] (32768 floats)

// ---------------------------------------------------------------------------
// Generic tiled fp32 GEMM body: C[M,N] = A[M,K] @ op(W) + bias + add
//   WT=true : op(W) = W^T where W is [N,K] row-major (ldw = K)
//   WT=false: op(W) = W   where W is [K,N] row-major (ldw = N)
// add (optional): row stride addstride, added elementwise.
// M % BM == 0, N % BN == 0 assumed. K arbitrary.
// ---------------------------------------------------------------------------
template<int BM, int BN, int BK, int TM, int TN, bool WT>
__device__ __forceinline__ void gemm_body(
    const float* __restrict__ A, int lda,
    const float* __restrict__ W, int ldw,
    const float* __restrict__ bias,
    const float* __restrict__ add, long addstride,
    float* __restrict__ C, long ldc,
    int M, int N, int K)
{
    __shared__ float As[BK][BM];
    __shared__ float Bs[BK][BN];

    const int tid = threadIdx.x;
    constexpr int NT = (BM / TM) * (BN / TN);   // threads per block (256)
    const int bm = blockIdx.y * BM;
    const int bn = blockIdx.x * BN;
    const int tn = (tid % (BN / TN)) * TN;
    const int tm = (tid / (BN / TN)) * TM;

    float acc[TM][TN];
#pragma unroll
    for (int i = 0; i < TM; ++i)
#pragma unroll
        for (int j = 0; j < TN; ++j) acc[i][j] = 0.f;

    for (int k0 = 0; k0 < K; k0 += BK) {
        const int kw = (K - k0 < BK) ? (K - k0) : BK;
        // Load A tile (k fastest within a row -> chunks of contiguous loads)
        for (int i = tid; i < BM * BK; i += NT) {
            int m = i / BK, k = i % BK;
            As[k][m] = (k < kw) ? A[(size_t)(bm + m) * lda + (k0 + k)] : 0.f;
        }
        // Load W tile
        if (WT) {
            for (int i = tid; i < BN * BK; i += NT) {
                int n = i / BK, k = i % BK;
                Bs[k][n] = (k < kw) ? W[(size_t)(bn + n) * ldw + (k0 + k)] : 0.f;
            }
        } else {
            for (int i = tid; i < BN * BK; i += NT) {
                int k = i / BN, n = i % BN;
                Bs[k][n] = (k < kw) ? W[(size_t)(k0 + k) * ldw + (bn + n)] : 0.f;
            }
        }
        __syncthreads();
#pragma unroll
        for (int k = 0; k < BK; ++k) {
            float a[TM], b[TN];
#pragma unroll
            for (int i = 0; i < TM; ++i) a[i] = As[k][tm + i];
#pragma unroll
            for (int j = 0; j < TN; ++j) b[j] = Bs[k][tn + j];
#pragma unroll
            for (int i = 0; i < TM; ++i)
#pragma unroll
                for (int j = 0; j < TN; ++j)
                    acc[i][j] = fmaf(a[i], b[j], acc[i][j]);
        }
        __syncthreads();
    }

#pragma unroll
    for (int i = 0; i < TM; ++i) {
        int m = bm + tm + i;
#pragma unroll
        for (int j = 0; j < TN; ++j) {
            int n = bn + tn + j;
            float v = acc[i][j];
            if (bias) v += bias[n];
            if (add)  v += add[(size_t)m * addstride + n];
            C[(size_t)m * ldc + n] = v;
        }
    }
}

template<int BM, int BN, int BK, int TM, int TN, bool WT>
__global__ void __launch_bounds__(256)
gemm_gg(const float* __restrict__ A, int lda,
        const float* __restrict__ W, int ldw,
        const float* __restrict__ bias,
        const float* __restrict__ add, long addstride,
        float* __restrict__ C, long ldc,
        int M, int N, int K)
{
    gemm_body<BM, BN, BK, TM, TN, WT>(A, lda, W, ldw, bias, add, addstride,
                                      C, ldc, M, N, K);
}

// One LSTM recurrence GEMM step, both directions (blockIdx.z picks dir):
//   z = h_prev @ w_hh^T + xproj[:, t_eff, :]
// M=128, N=2048, K=512
template<int BM, int BN, int BK, int TM, int TN>
__global__ void __launch_bounds__(256)
lstm_z(const float* __restrict__ hf, const float* __restrict__ hb,
       const float* __restrict__ whf, const float* __restrict__ whb,
       const float* __restrict__ addf, const float* __restrict__ addb,
       float* __restrict__ zf, float* __restrict__ zb)
{
    const bool back = (blockIdx.z != 0);
    gemm_body<BM, BN, BK, TM, TN, true>(
        back ? hb : hf, 512,
        back ? whb : whf, 512,
        nullptr,
        back ? addb : addf, 524288L,   // row stride of xproj = T*4H
        back ? zb : zf, 2048L,
        128, 2048, 512);
}

// Pointwise LSTM gate update for both directions.
// idx = dir*65536 + b*512 + j ; states laid out [2][128][512]
__global__ void __launch_bounds__(256)
lstm_gates(const float* __restrict__ zf, const float* __restrict__ zb,
           float* __restrict__ hst, float* __restrict__ cst,
           float* __restrict__ out, int t)
{
    int idx = blockIdx.x * 256 + threadIdx.x;   // 131072 threads
    int dir = idx >> 16;
    int r = idx & 0xFFFF;
    int b = r >> 9;
    int j = r & 511;
    const float* z = dir ? zb : zf;
    size_t zoff = (size_t)b * 2048;
    float zi = z[zoff + j];
    float zff = z[zoff + 512 + j];
    float zg = z[zoff + 1024 + j];
    float zo = z[zoff + 1536 + j];
    float c = cst[idx];
    float is = 1.f / (1.f + expf(-zi));
    float fs = 1.f / (1.f + expf(-zff));
    float g  = tanhf(zg);
    float os = 1.f / (1.f + expf(-zo));
    c = fs * c + is * g;
    float h = os * tanhf(c);
    cst[idx] = c;
    hst[idx] = h;
    int teff = dir ? (255 - t) : t;
    out[((size_t)b * 256 + teff) * 1024 + (size_t)dir * 512 + j] = h;
}

// scores[row] = sum_j tanh(hidden[row, j]) * aw2[j] + ab2 ; row = b*T + t
__global__ void __launch_bounds__(256)
att_score(const float* __restrict__ hidden, const float* __restrict__ aw2,
          const float* __restrict__ ab2, float* __restrict__ scores)
{
    int row = blockIdx.x;
    const float* hrow = hidden + (size_t)row * 1024;
    int tid = threadIdx.x;
    float s = 0.f;
    for (int j = tid; j < 1024; j += 256)
        s += tanhf(hrow[j]) * aw2[j];
    for (int off = 32; off > 0; off >>= 1) s += __shfl_down(s, off);
    __shared__ float red[4];
    if ((tid & 63) == 0) red[tid >> 6] = s;
    __syncthreads();
    if (tid == 0)
        scores[row] = red[0] + red[1] + red[2] + red[3] + ab2[0];
}

// Softmax over T=256 per batch row; writes normalized weights in place and to d_out.
__global__ void __launch_bounds__(256)
att_softmax(float* __restrict__ scores, float* __restrict__ attw_out)
{
    int b = blockIdx.x, t = threadIdx.x;
    float v = scores[b * 256 + t];
    __shared__ float red[4];
    float m = v;
    for (int off = 32; off > 0; off >>= 1) m = fmaxf(m, __shfl_down(m, off));
    if ((t & 63) == 0) red[t >> 6] = m;
    __syncthreads();
    float bmax = fmaxf(fmaxf(red[0], red[1]), fmaxf(red[2], red[3]));
    __syncthreads();
    float e = expf(v - bmax);
    float s = e;
    for (int off = 32; off > 0; off >>= 1) s += __shfl_down(s, off);
    if ((t & 63) == 0) red[t >> 6] = s;
    __syncthreads();
    float bsum = red[0] + red[1] + red[2] + red[3];
    float w = e / bsum;
    scores[b * 256 + t] = w;
    attw_out[b * 256 + t] = w;
}

// context[b, j] = sum_t attw[b,t] * lstm_out[b,t,j]
__global__ void __launch_bounds__(256)
att_context(const float* __restrict__ attw, const float* __restrict__ lout,
            float* __restrict__ ctx)
{
    int b = blockIdx.y;
    int j = blockIdx.x * 256 + threadIdx.x;   // 1024 cols
    float s = 0.f;
    for (int t = 0; t < 256; ++t)
        s += attw[b * 256 + t] * lout[((size_t)b * 256 + t) * 1024 + j];
    ctx[(size_t)b * 1024 + j] = s;
}

// hidden2 = relu(context @ cw1 + cb1): [128,1024]@[1024,512]
__global__ void __launch_bounds__(256)
fc1_kernel(const float* __restrict__ ctx, const float* __restrict__ cw1,
           const float* __restrict__ cb1, float* __restrict__ hid2)
{
    int idx = blockIdx.x * 256 + threadIdx.x;  // 65536
    int b = idx >> 9, n = idx & 511;
    float s = cb1[n];
    const float* cr = ctx + (size_t)b * 1024;
    for (int k = 0; k < 1024; ++k)
        s = fmaf(cr[k], cw1[(size_t)k * 512 + n], s);
    hid2[idx] = fmaxf(s, 0.f);
}

// logits = hidden2 @ cw2 + cb2: [128,512]@[512,100]
__global__ void __launch_bounds__(256)
fc2_kernel(const float* __restrict__ hid2, const float* __restrict__ cw2,
           const float* __restrict__ cb2, float* __restrict__ logits)
{
    int idx = blockIdx.x * 256 + threadIdx.x;
    if (idx >= 12800) return;
    int b = idx / 100, n = idx % 100;
    float s = cb2[n];
    const float* hr = hid2 + (size_t)b * 512;
    for (int k = 0; k < 512; ++k)
        s = fmaf(hr[k], cw2[(size_t)k * 100 + n], s);
    logits[idx] = s;
}

extern "C" void kernel_launch(void* const* d_in, const int* in_sizes, int n_in,
                              void* d_out, int out_size, void* d_ws, size_t ws_size,
                              hipStream_t stream)
{
    const float* x        = (const float*)d_in[0];
    const float* w_ih_l0f = (const float*)d_in[1];
    const float* w_hh_l0f = (const float*)d_in[2];
    const float* b_l0f    = (const float*)d_in[3];
    const float* w_ih_l0b = (const float*)d_in[4];
    const float* w_hh_l0b = (const float*)d_in[5];
    const float* b_l0b    = (const float*)d_in[6];
    const float* w_ih_l1f = (const float*)d_in[7];
    const float* w_hh_l1f = (const float*)d_in[8];
    const float* b_l1f    = (const float*)d_in[9];
    const float* w_ih_l1b = (const float*)d_in[10];
    const float* w_hh_l1b = (const float*)d_in[11];
    const float* b_l1b    = (const float*)d_in[12];
    const float* aw1      = (const float*)d_in[13];
    const float* ab1      = (const float*)d_in[14];
    const float* aw2      = (const float*)d_in[15];
    const float* ab2      = (const float*)d_in[16];
    const float* cw1      = (const float*)d_in[17];
    const float* cb1      = (const float*)d_in[18];
    const float* cw2      = (const float*)d_in[19];
    const float* cb2      = (const float*)d_in[20];

    // Workspace layout (floats). Total ~772 MiB.
    float* ws   = (float*)d_ws;
    float* bufA = ws;                      // 67,108,864  xproj0f / xproj1f / att-hidden
    float* bufB = bufA + 67108864;         // 67,108,864  xproj0b / xproj1b
    float* h0   = bufB + 67108864;         // 33,554,432  layer0 output [B,T,1024]
    float* lout = h0   + 33554432;         // 33,554,432  layer1 output [B,T,1024]
    float* zf   = lout + 33554432;         // 262,144     z fwd [128,2048]
    float* zb   = zf   + 262144;           // 262,144     z bwd
    float* hst  = zb   + 262144;           // 131,072     h state [2][128][512]
    float* cst  = hst  + 131072;           // 131,072     c state
    float* scores = cst + 131072;          // 32,768
    float* ctx  = scores + 32768;          // 131,072
    float* hid2 = ctx  + 131072;           // 65,536

    float* logits   = (float*)d_out;       // [128,100]
    float* attw_out = logits + 12800;      // [128,256]

    dim3 blk(256);

    // ---- Layer 0 input projections: [32768,1662] @ [2048,1662]^T + b ----
    gemm_gg<64, 64, 16, 4, 4, true><<<dim3(2048 / 64, 32768 / 64), blk, 0, stream>>>(
        x, 1662, w_ih_l0f, 1662, b_l0f, nullptr, 0L, bufA, 2048L, 32768, 2048, 1662);
    gemm_gg<64, 64, 16, 4, 4, true><<<dim3(2048 / 64, 32768 / 64), blk, 0, stream>>>(
        x, 1662, w_ih_l0b, 1662, b_l0b, nullptr, 0L, bufB, 2048L, 32768, 2048, 1662);

    // ---- Layer 0 recurrence ----
    hipMemsetAsync(hst, 0, 131072 * sizeof(float), stream);
    hipMemsetAsync(cst, 0, 131072 * sizeof(float), stream);
    for (int t = 0; t < 256; ++t) {
        lstm_z<64, 32, 16, 4, 2><<<dim3(2048 / 32, 2, 2), blk, 0, stream>>>(
            hst, hst + 65536, w_hh_l0f, w_hh_l0b,
            bufA + (size_t)t * 2048, bufB + (size_t)(255 - t) * 2048, zf, zb);
        lstm_gates<<<512, blk, 0, stream>>>(zf, zb, hst, cst, h0, t);
    }

    // ---- Layer 1 input projections: [32768,1024] @ [2048,1024]^T + b ----
    gemm_gg<64, 64, 16, 4, 4, true><<<dim3(2048 / 64, 32768 / 64), blk, 0, stream>>>(
        h0, 1024, w_ih_l1f, 1024, b_l1f, nullptr, 0L, bufA, 2048L, 32768, 2048, 1024);
    gemm_gg<64, 64, 16, 4, 4, true><<<dim3(2048 / 64, 32768 / 64), blk, 0, stream>>>(
        h0, 1024, w_ih_l1b, 1024, b_l1b, nullptr, 0L, bufB, 2048L, 32768, 2048, 1024);

    // ---- Layer 1 recurrence ----
    hipMemsetAsync(hst, 0, 131072 * sizeof(float), stream);
    hipMemsetAsync(cst, 0, 131072 * sizeof(float), stream);
    for (int t = 0; t < 256; ++t) {
        lstm_z<64, 32, 16, 4, 2><<<dim3(2048 / 32, 2, 2), blk, 0, stream>>>(
            hst, hst + 65536, w_hh_l1f, w_hh_l1b,
            bufA + (size_t)t * 2048, bufB + (size_t)(255 - t) * 2048, zf, zb);
        lstm_gates<<<512, blk, 0, stream>>>(zf, zb, hst, cst, lout, t);
    }

    // ---- Attention: hidden = lstm_out @ aw1 + ab1 (NN GEMM, [32768,1024]@[1024,1024]) ----
    gemm_gg<64, 64, 16, 4, 4, false><<<dim3(1024 / 64, 32768 / 64), blk, 0, stream>>>(
        lout, 1024, aw1, 1024, ab1, nullptr, 0L, bufA, 1024L, 32768, 1024, 1024);

    att_score<<<32768, blk, 0, stream>>>(bufA, aw2, ab2, scores);
    att_softmax<<<128, blk, 0, stream>>>(scores, attw_out);
    att_context<<<dim3(4, 128), blk, 0, stream>>>(scores, lout, ctx);

    // ---- Classifier ----
    fc1_kernel<<<256, blk, 0, stream>>>(ctx, cw1, cb1, hid2);
    fc2_kernel<<<50, blk, 0, stream>>>(hid2, cw2, cb2, logits);
}

// Round 2
// 36992.377 us; speedup vs baseline: 1.2952x; 1.2952x over previous
//
#include <hip/hip_runtime.h>
#include <math.h>

// Problem constants: IN=1662, H=512, T=256, B=128, C=100
// Outputs: logits [128,100] then attw [128,256,1]

typedef __attribute__((ext_vector_type(8))) short bf16x8;
typedef __attribute__((ext_vector_type(4))) float f32x4;

__device__ __forceinline__ ushort f2bf(float f) {
    uint u = __float_as_uint(f);
    uint r = (u + 0x7FFFu + ((u >> 16) & 1u)) >> 16;
    return (ushort)r;
}
__device__ __forceinline__ float bf2f(ushort h) {
    return __uint_as_float(((uint)h) << 16);
}

// ---------------------------------------------------------------------------
// Split-bf16 MFMA GEMM: C[M,N] = A[M,K] @ W^T + bias
//   A: [M,K] row-major (lda), W: [N,K] row-major (ldw)
//   fp32 accuracy via hi/lo bf16 split: hi*hi + hi*lo + lo*hi
//   BM=BN=128, BK=32, 256 threads (4 waves, each 64x64 via 4x4 16x16x32 MFMA)
//   M,N must be multiples of 128; K arbitrary even.
// ---------------------------------------------------------------------------
__global__ void __launch_bounds__(256, 2)
gemm_mfma_bt(const float* __restrict__ A, int lda,
             const float* __restrict__ W, int ldw,
             const float* __restrict__ bias,
             float* __restrict__ C, long ldc, int K)
{
    __shared__ ushort Ahi[128][40];
    __shared__ ushort Alo[128][40];
    __shared__ ushort Bhi[128][40];
    __shared__ ushort Blo[128][40];

    const int tid  = threadIdx.x;
    const int bm   = blockIdx.y * 128;
    const int bn   = blockIdx.x * 128;
    const int wave = tid >> 6, lane = tid & 63;
    const int wr = wave >> 1, wc = wave & 1;
    const int quad = lane >> 4, l16 = lane & 15;

    f32x4 acc[4][4];
#pragma unroll
    for (int i = 0; i < 4; ++i)
#pragma unroll
        for (int j = 0; j < 4; ++j)
            acc[i][j] = (f32x4){0.f, 0.f, 0.f, 0.f};

    for (int k0 = 0; k0 < K; k0 += 32) {
        const int kw = (K - k0 < 32) ? (K - k0) : 32;
        // Stage A tile: 128 rows x 32 k, as 2048 float2 -> 8 per thread
#pragma unroll
        for (int i = 0; i < 8; ++i) {
            int f = i * 256 + tid;
            int row = f >> 4, kp = f & 15;
            float2 v = make_float2(0.f, 0.f);
            if (2 * kp < kw)
                v = *(const float2*)(A + (size_t)(bm + row) * lda + k0 + 2 * kp);
            ushort hx = f2bf(v.x), hy = f2bf(v.y);
            ushort lx = f2bf(v.x - bf2f(hx)), ly = f2bf(v.y - bf2f(hy));
            *(uint*)&Ahi[row][2 * kp] = (uint)hx | ((uint)hy << 16);
            *(uint*)&Alo[row][2 * kp] = (uint)lx | ((uint)ly << 16);
        }
        // Stage B tile (W rows bn..bn+127)
#pragma unroll
        for (int i = 0; i < 8; ++i) {
            int f = i * 256 + tid;
            int row = f >> 4, kp = f & 15;
            float2 v = make_float2(0.f, 0.f);
            if (2 * kp < kw)
                v = *(const float2*)(W + (size_t)(bn + row) * ldw + k0 + 2 * kp);
            ushort hx = f2bf(v.x), hy = f2bf(v.y);
            ushort lx = f2bf(v.x - bf2f(hx)), ly = f2bf(v.y - bf2f(hy));
            *(uint*)&Bhi[row][2 * kp] = (uint)hx | ((uint)hy << 16);
            *(uint*)&Blo[row][2 * kp] = (uint)lx | ((uint)ly << 16);
        }
        __syncthreads();

        bf16x8 ah[4], al[4], bh[4], bl[4];
#pragma unroll
        for (int i = 0; i < 4; ++i) {
            int m = wr * 64 + i * 16 + l16;
            ah[i] = *(const bf16x8*)&Ahi[m][quad * 8];
            al[i] = *(const bf16x8*)&Alo[m][quad * 8];
            int n = wc * 64 + i * 16 + l16;
            bh[i] = *(const bf16x8*)&Bhi[n][quad * 8];
            bl[i] = *(const bf16x8*)&Blo[n][quad * 8];
        }
#pragma unroll
        for (int i = 0; i < 4; ++i)
#pragma unroll
            for (int j = 0; j < 4; ++j) {
                acc[i][j] = __builtin_amdgcn_mfma_f32_16x16x32_bf16(ah[i], bh[j], acc[i][j], 0, 0, 0);
                acc[i][j] = __builtin_amdgcn_mfma_f32_16x16x32_bf16(ah[i], bl[j], acc[i][j], 0, 0, 0);
                acc[i][j] = __builtin_amdgcn_mfma_f32_16x16x32_bf16(al[i], bh[j], acc[i][j], 0, 0, 0);
            }
        __syncthreads();
    }

    // Epilogue: C/D layout col=lane&15, row=quad*4+reg (m89-verified)
#pragma unroll
    for (int j = 0; j < 4; ++j) {
        int n = bn + wc * 64 + j * 16 + l16;
        float bv = bias ? bias[n] : 0.f;
#pragma unroll
        for (int i = 0; i < 4; ++i) {
            int mb = bm + wr * 64 + i * 16 + quad * 4;
#pragma unroll
            for (int r = 0; r < 4; ++r)
                C[(size_t)(mb + r) * ldc + n] = acc[i][j][r] + bv;
        }
    }
}

// 1024x1024 transpose: out[n][k] = in[k][n]
__global__ void __launch_bounds__(256)
transpose1024(const float* __restrict__ in, float* __restrict__ out)
{
    __shared__ float tile[32][33];
    int bx = blockIdx.x * 32, by = blockIdx.y * 32;
    int tx = threadIdx.x & 31, ty = threadIdx.x >> 5;   // 32x8
    for (int i = 0; i < 32; i += 8)
        tile[ty + i][tx] = in[(size_t)(by + ty + i) * 1024 + bx + tx];
    __syncthreads();
    for (int i = 0; i < 32; i += 8)
        out[(size_t)(bx + ty + i) * 1024 + by + tx] = tile[tx][ty + i];
}

// ---------------------------------------------------------------------------
// fp32 tiled GEMM body (kept for the recurrence z-step)
// ---------------------------------------------------------------------------
template<int BM, int BN, int BK, int TM, int TN>
__device__ __forceinline__ void gemm_body(
    const float* __restrict__ A, int lda,
    const float* __restrict__ W, int ldw,
    const float* __restrict__ add, long addstride,
    float* __restrict__ C, long ldc,
    int M, int N, int K)
{
    __shared__ float As[BK][BM];
    __shared__ float Bs[BK][BN];

    const int tid = threadIdx.x;
    constexpr int NT = (BM / TM) * (BN / TN);
    const int bm = blockIdx.y * BM;
    const int bn = blockIdx.x * BN;
    const int tn = (tid % (BN / TN)) * TN;
    const int tm = (tid / (BN / TN)) * TM;

    float acc[TM][TN];
#pragma unroll
    for (int i = 0; i < TM; ++i)
#pragma unroll
        for (int j = 0; j < TN; ++j) acc[i][j] = 0.f;

    for (int k0 = 0; k0 < K; k0 += BK) {
        for (int i = tid; i < BM * BK; i += NT) {
            int m = i / BK, k = i % BK;
            As[k][m] = A[(size_t)(bm + m) * lda + (k0 + k)];
        }
        for (int i = tid; i < BN * BK; i += NT) {
            int n = i / BK, k = i % BK;
            Bs[k][n] = W[(size_t)(bn + n) * ldw + (k0 + k)];
        }
        __syncthreads();
#pragma unroll
        for (int k = 0; k < BK; ++k) {
            float a[TM], b[TN];
#pragma unroll
            for (int i = 0; i < TM; ++i) a[i] = As[k][tm + i];
#pragma unroll
            for (int j = 0; j < TN; ++j) b[j] = Bs[k][tn + j];
#pragma unroll
            for (int i = 0; i < TM; ++i)
#pragma unroll
                for (int j = 0; j < TN; ++j)
                    acc[i][j] = fmaf(a[i], b[j], acc[i][j]);
        }
        __syncthreads();
    }

#pragma unroll
    for (int i = 0; i < TM; ++i) {
        int m = bm + tm + i;
#pragma unroll
        for (int j = 0; j < TN; ++j) {
            int n = bn + tn + j;
            C[(size_t)m * ldc + n] = acc[i][j] + add[(size_t)m * addstride + n];
        }
    }
}

// One LSTM recurrence GEMM step, both directions: z = h @ w_hh^T + xproj[:,t,:]
template<int BM, int BN, int BK, int TM, int TN>
__global__ void __launch_bounds__(256)
lstm_z(const float* __restrict__ hf, const float* __restrict__ hb,
       const float* __restrict__ whf, const float* __restrict__ whb,
       const float* __restrict__ addf, const float* __restrict__ addb,
       float* __restrict__ zf, float* __restrict__ zb)
{
    const bool back = (blockIdx.z != 0);
    gemm_body<BM, BN, BK, TM, TN>(
        back ? hb : hf, 512,
        back ? whb : whf, 512,
        back ? addb : addf, 524288L,
        back ? zb : zf, 2048L,
        128, 2048, 512);
}

// Pointwise LSTM gate update, both directions. states [2][128][512]
__global__ void __launch_bounds__(256)
lstm_gates(const float* __restrict__ zf, const float* __restrict__ zb,
           float* __restrict__ hst, float* __restrict__ cst,
           float* __restrict__ out, int t)
{
    int idx = blockIdx.x * 256 + threadIdx.x;   // 131072 threads
    int dir = idx >> 16;
    int r = idx & 0xFFFF;
    int b = r >> 9;
    int j = r & 511;
    const float* z = dir ? zb : zf;
    size_t zoff = (size_t)b * 2048;
    float zi = z[zoff + j];
    float zff = z[zoff + 512 + j];
    float zg = z[zoff + 1024 + j];
    float zo = z[zoff + 1536 + j];
    float c = cst[idx];
    float is = 1.f / (1.f + expf(-zi));
    float fs = 1.f / (1.f + expf(-zff));
    float g  = tanhf(zg);
    float os = 1.f / (1.f + expf(-zo));
    c = fs * c + is * g;
    float h = os * tanhf(c);
    cst[idx] = c;
    hst[idx] = h;
    int teff = dir ? (255 - t) : t;
    out[((size_t)b * 256 + teff) * 1024 + (size_t)dir * 512 + j] = h;
}

// scores[row] = sum_j tanh(hidden[row,j]) * aw2[j] + ab2
__global__ void __launch_bounds__(256)
att_score(const float* __restrict__ hidden, const float* __restrict__ aw2,
          const float* __restrict__ ab2, float* __restrict__ scores)
{
    int row = blockIdx.x;
    const float* hrow = hidden + (size_t)row * 1024;
    int tid = threadIdx.x;
    float s = 0.f;
    for (int j = tid; j < 1024; j += 256)
        s += tanhf(hrow[j]) * aw2[j];
    for (int off = 32; off > 0; off >>= 1) s += __shfl_down(s, off);
    __shared__ float red[4];
    if ((tid & 63) == 0) red[tid >> 6] = s;
    __syncthreads();
    if (tid == 0)
        scores[row] = red[0] + red[1] + red[2] + red[3] + ab2[0];
}

__global__ void __launch_bounds__(256)
att_softmax(float* __restrict__ scores, float* __restrict__ attw_out)
{
    int b = blockIdx.x, t = threadIdx.x;
    float v = scores[b * 256 + t];
    __shared__ float red[4];
    float m = v;
    for (int off = 32; off > 0; off >>= 1) m = fmaxf(m, __shfl_down(m, off));
    if ((t & 63) == 0) red[t >> 6] = m;
    __syncthreads();
    float bmax = fmaxf(fmaxf(red[0], red[1]), fmaxf(red[2], red[3]));
    __syncthreads();
    float e = expf(v - bmax);
    float s = e;
    for (int off = 32; off > 0; off >>= 1) s += __shfl_down(s, off);
    if ((t & 63) == 0) red[t >> 6] = s;
    __syncthreads();
    float bsum = red[0] + red[1] + red[2] + red[3];
    float w = e / bsum;
    scores[b * 256 + t] = w;
    attw_out[b * 256 + t] = w;
}

__global__ void __launch_bounds__(256)
att_context(const float* __restrict__ attw, const float* __restrict__ lout,
            float* __restrict__ ctx)
{
    int b = blockIdx.y;
    int j = blockIdx.x * 256 + threadIdx.x;
    float s = 0.f;
    for (int t = 0; t < 256; ++t)
        s += attw[b * 256 + t] * lout[((size_t)b * 256 + t) * 1024 + j];
    ctx[(size_t)b * 1024 + j] = s;
}

__global__ void __launch_bounds__(256)
fc1_kernel(const float* __restrict__ ctx, const float* __restrict__ cw1,
           const float* __restrict__ cb1, float* __restrict__ hid2)
{
    int idx = blockIdx.x * 256 + threadIdx.x;
    int b = idx >> 9, n = idx & 511;
    float s = cb1[n];
    const float* cr = ctx + (size_t)b * 1024;
    for (int k = 0; k < 1024; ++k)
        s = fmaf(cr[k], cw1[(size_t)k * 512 + n], s);
    hid2[idx] = fmaxf(s, 0.f);
}

__global__ void __launch_bounds__(256)
fc2_kernel(const float* __restrict__ hid2, const float* __restrict__ cw2,
           const float* __restrict__ cb2, float* __restrict__ logits)
{
    int idx = blockIdx.x * 256 + threadIdx.x;
    if (idx >= 12800) return;
    int b = idx / 100, n = idx % 100;
    float s = cb2[n];
    const float* hr = hid2 + (size_t)b * 512;
    for (int k = 0; k < 512; ++k)
        s = fmaf(hr[k], cw2[(size_t)k * 100 + n], s);
    logits[idx] = s;
}

extern "C" void kernel_launch(void* const* d_in, const int* in_sizes, int n_in,
                              void* d_out, int out_size, void* d_ws, size_t ws_size,
                              hipStream_t stream)
{
    const float* x        = (const float*)d_in[0];
    const float* w_ih_l0f = (const float*)d_in[1];
    const float* w_hh_l0f = (const float*)d_in[2];
    const float* b_l0f    = (const float*)d_in[3];
    const float* w_ih_l0b = (const float*)d_in[4];
    const float* w_hh_l0b = (const float*)d_in[5];
    const float* b_l0b    = (const float*)d_in[6];
    const float* w_ih_l1f = (const float*)d_in[7];
    const float* w_hh_l1f = (const float*)d_in[8];
    const float* b_l1f    = (const float*)d_in[9];
    const float* w_ih_l1b = (const float*)d_in[10];
    const float* w_hh_l1b = (const float*)d_in[11];
    const float* b_l1b    = (const float*)d_in[12];
    const float* aw1      = (const float*)d_in[13];
    const float* ab1      = (const float*)d_in[14];
    const float* aw2      = (const float*)d_in[15];
    const float* ab2      = (const float*)d_in[16];
    const float* cw1      = (const float*)d_in[17];
    const float* cb1      = (const float*)d_in[18];
    const float* cw2      = (const float*)d_in[19];
    const float* cb2      = (const float*)d_in[20];

    float* ws   = (float*)d_ws;
    float* bufA = ws;                      // 67,108,864 floats
    float* bufB = bufA + 67108864;         // 67,108,864 (also holds aw1^T later)
    float* h0   = bufB + 67108864;         // 33,554,432  layer0 out [B,T,1024]
    float* lout = h0   + 33554432;         // 33,554,432  layer1 out [B,T,1024]
    float* zf   = lout + 33554432;         // 262,144
    float* zb   = zf   + 262144;           // 262,144
    float* hst  = zb   + 262144;           // 131,072
    float* cst  = hst  + 131072;           // 131,072
    float* scores = cst + 131072;          // 32,768
    float* ctx  = scores + 32768;          // 131,072
    float* hid2 = ctx  + 131072;           // 65,536

    float* logits   = (float*)d_out;
    float* attw_out = logits + 12800;

    dim3 blk(256);

    // ---- Layer 0 input projections: [32768,1662] @ [2048,1662]^T + b ----
    gemm_mfma_bt<<<dim3(16, 256), blk, 0, stream>>>(x, 1662, w_ih_l0f, 1662, b_l0f, bufA, 2048L, 1662);
    gemm_mfma_bt<<<dim3(16, 256), blk, 0, stream>>>(x, 1662, w_ih_l0b, 1662, b_l0b, bufB, 2048L, 1662);

    // ---- Layer 0 recurrence ----
    hipMemsetAsync(hst, 0, 131072 * sizeof(float), stream);
    hipMemsetAsync(cst, 0, 131072 * sizeof(float), stream);
    for (int t = 0; t < 256; ++t) {
        lstm_z<64, 32, 16, 4, 2><<<dim3(2048 / 32, 2, 2), blk, 0, stream>>>(
            hst, hst + 65536, w_hh_l0f, w_hh_l0b,
            bufA + (size_t)t * 2048, bufB + (size_t)(255 - t) * 2048, zf, zb);
        lstm_gates<<<512, blk, 0, stream>>>(zf, zb, hst, cst, h0, t);
    }

    // ---- Layer 1 input projections: [32768,1024] @ [2048,1024]^T + b ----
    gemm_mfma_bt<<<dim3(16, 256), blk, 0, stream>>>(h0, 1024, w_ih_l1f, 1024, b_l1f, bufA, 2048L, 1024);
    gemm_mfma_bt<<<dim3(16, 256), blk, 0, stream>>>(h0, 1024, w_ih_l1b, 1024, b_l1b, bufB, 2048L, 1024);

    // ---- Layer 1 recurrence ----
    hipMemsetAsync(hst, 0, 131072 * sizeof(float), stream);
    hipMemsetAsync(cst, 0, 131072 * sizeof(float), stream);
    for (int t = 0; t < 256; ++t) {
        lstm_z<64, 32, 16, 4, 2><<<dim3(2048 / 32, 2, 2), blk, 0, stream>>>(
            hst, hst + 65536, w_hh_l1f, w_hh_l1b,
            bufA + (size_t)t * 2048, bufB + (size_t)(255 - t) * 2048, zf, zb);
        lstm_gates<<<512, blk, 0, stream>>>(zf, zb, hst, cst, lout, t);
    }

    // ---- Attention: transpose aw1 into bufB (free now), then MFMA GEMM ----
    transpose1024<<<dim3(32, 32), blk, 0, stream>>>(aw1, bufB);
    gemm_mfma_bt<<<dim3(8, 256), blk, 0, stream>>>(lout, 1024, bufB, 1024, ab1, bufA, 1024L, 1024);

    att_score<<<32768, blk, 0, stream>>>(bufA, aw2, ab2, scores);
    att_softmax<<<128, blk, 0, stream>>>(scores, attw_out);
    att_context<<<dim3(4, 128), blk, 0, stream>>>(scores, lout, ctx);

    // ---- Classifier ----
    fc1_kernel<<<256, blk, 0, stream>>>(ctx, cw1, cb1, hid2);
    fc2_kernel<<<50, blk, 0, stream>>>(hid2, cw2, cb2, logits);
}

// Round 3
// 27135.809 us; speedup vs baseline: 1.7656x; 1.3632x over previous
//
#include <hip/hip_runtime.h>
#include <math.h>

// Problem constants: IN=1662, H=512, T=256, B=128, C=100
// Outputs: logits [128,100] then attw [128,256,1]

typedef __attribute__((ext_vector_type(8))) short bf16x8;
typedef __attribute__((ext_vector_type(4))) float f32x4;

__device__ __forceinline__ ushort f2bf(float f) {
    uint u = __float_as_uint(f);
    uint r = (u + 0x7FFFu + ((u >> 16) & 1u)) >> 16;
    return (ushort)r;
}
__device__ __forceinline__ float bf2f(ushort h) {
    return __uint_as_float(((uint)h) << 16);
}

// ---------------------------------------------------------------------------
// Split-bf16 MFMA GEMM: C[M,N] = A[M,K] @ W^T + bias   (unchanged from R2)
// ---------------------------------------------------------------------------
__global__ void __launch_bounds__(256, 2)
gemm_mfma_bt(const float* __restrict__ A, int lda,
             const float* __restrict__ W, int ldw,
             const float* __restrict__ bias,
             float* __restrict__ C, long ldc, int K)
{
    __shared__ ushort Ahi[128][40];
    __shared__ ushort Alo[128][40];
    __shared__ ushort Bhi[128][40];
    __shared__ ushort Blo[128][40];

    const int tid  = threadIdx.x;
    const int bm   = blockIdx.y * 128;
    const int bn   = blockIdx.x * 128;
    const int wave = tid >> 6, lane = tid & 63;
    const int wr = wave >> 1, wc = wave & 1;
    const int quad = lane >> 4, l16 = lane & 15;

    f32x4 acc[4][4];
#pragma unroll
    for (int i = 0; i < 4; ++i)
#pragma unroll
        for (int j = 0; j < 4; ++j)
            acc[i][j] = (f32x4){0.f, 0.f, 0.f, 0.f};

    for (int k0 = 0; k0 < K; k0 += 32) {
        const int kw = (K - k0 < 32) ? (K - k0) : 32;
#pragma unroll
        for (int i = 0; i < 8; ++i) {
            int f = i * 256 + tid;
            int row = f >> 4, kp = f & 15;
            float2 v = make_float2(0.f, 0.f);
            if (2 * kp < kw)
                v = *(const float2*)(A + (size_t)(bm + row) * lda + k0 + 2 * kp);
            ushort hx = f2bf(v.x), hy = f2bf(v.y);
            ushort lx = f2bf(v.x - bf2f(hx)), ly = f2bf(v.y - bf2f(hy));
            *(uint*)&Ahi[row][2 * kp] = (uint)hx | ((uint)hy << 16);
            *(uint*)&Alo[row][2 * kp] = (uint)lx | ((uint)ly << 16);
        }
#pragma unroll
        for (int i = 0; i < 8; ++i) {
            int f = i * 256 + tid;
            int row = f >> 4, kp = f & 15;
            float2 v = make_float2(0.f, 0.f);
            if (2 * kp < kw)
                v = *(const float2*)(W + (size_t)(bn + row) * ldw + k0 + 2 * kp);
            ushort hx = f2bf(v.x), hy = f2bf(v.y);
            ushort lx = f2bf(v.x - bf2f(hx)), ly = f2bf(v.y - bf2f(hy));
            *(uint*)&Bhi[row][2 * kp] = (uint)hx | ((uint)hy << 16);
            *(uint*)&Blo[row][2 * kp] = (uint)lx | ((uint)ly << 16);
        }
        __syncthreads();

        bf16x8 ah[4], al[4], bh[4], bl[4];
#pragma unroll
        for (int i = 0; i < 4; ++i) {
            int m = wr * 64 + i * 16 + l16;
            ah[i] = *(const bf16x8*)&Ahi[m][quad * 8];
            al[i] = *(const bf16x8*)&Alo[m][quad * 8];
            int n = wc * 64 + i * 16 + l16;
            bh[i] = *(const bf16x8*)&Bhi[n][quad * 8];
            bl[i] = *(const bf16x8*)&Blo[n][quad * 8];
        }
#pragma unroll
        for (int i = 0; i < 4; ++i)
#pragma unroll
            for (int j = 0; j < 4; ++j) {
                acc[i][j] = __builtin_amdgcn_mfma_f32_16x16x32_bf16(ah[i], bh[j], acc[i][j], 0, 0, 0);
                acc[i][j] = __builtin_amdgcn_mfma_f32_16x16x32_bf16(ah[i], bl[j], acc[i][j], 0, 0, 0);
                acc[i][j] = __builtin_amdgcn_mfma_f32_16x16x32_bf16(al[i], bh[j], acc[i][j], 0, 0, 0);
            }
        __syncthreads();
    }

#pragma unroll
    for (int j = 0; j < 4; ++j) {
        int n = bn + wc * 64 + j * 16 + l16;
        float bv = bias ? bias[n] : 0.f;
#pragma unroll
        for (int i = 0; i < 4; ++i) {
            int mb = bm + wr * 64 + i * 16 + quad * 4;
#pragma unroll
            for (int r = 0; r < 4; ++r)
                C[(size_t)(mb + r) * ldc + n] = acc[i][j][r] + bv;
        }
    }
}

// 1024x1024 transpose: out[n][k] = in[k][n]
__global__ void __launch_bounds__(256)
transpose1024(const float* __restrict__ in, float* __restrict__ out)
{
    __shared__ float tile[32][33];
    int bx = blockIdx.x * 32, by = blockIdx.y * 32;
    int tx = threadIdx.x & 31, ty = threadIdx.x >> 5;
    for (int i = 0; i < 32; i += 8)
        tile[ty + i][tx] = in[(size_t)(by + ty + i) * 1024 + bx + tx];
    __syncthreads();
    for (int i = 0; i < 32; i += 8)
        out[(size_t)(bx + ty + i) * 1024 + by + tx] = tile[tx][ty + i];
}

// ---------------------------------------------------------------------------
// Pack w_hh [2048,512] fp32 (one direction) -> gate-packed split-bf16 planes
//   dest layout [32 jg][64 p][512 k], p = g*16 + jj, row = g*512 + jg*16 + jj
// ---------------------------------------------------------------------------
__global__ void __launch_bounds__(256)
pack_whh(const float* __restrict__ w, ushort* __restrict__ hi, ushort* __restrict__ lo)
{
    int idx = blockIdx.x * 256 + threadIdx.x;     // 2048*256 = 524288
    int r = idx >> 8;
    int kp = (idx & 255) * 2;
    float2 v = *(const float2*)&w[(size_t)r * 512 + kp];
    int g = r >> 9, j = r & 511, jg = j >> 4, jj = j & 15;
    int p = g * 16 + jj;
    size_t o = ((size_t)jg * 64 + p) * 512 + kp;
    ushort hx = f2bf(v.x), hy = f2bf(v.y);
    *(uint*)&hi[o] = (uint)hx | ((uint)hy << 16);
    *(uint*)&lo[o] = (uint)f2bf(v.x - bf2f(hx)) | ((uint)f2bf(v.y - bf2f(hy)) << 16);
}

// ---------------------------------------------------------------------------
// Fused LSTM step, both directions, one timestep.
// Grid: 64 blocks x 256 threads. dir = blk>>5, jg = blk&31 (16 j's per block).
// z[128b, 4 gates x 16 j] = h_prev(split-bf16) @ Whh_packed^T + xproj; then
// gates, c update, h written as split-bf16 (ping-pong) + fp32 to sequence out.
// ---------------------------------------------------------------------------
__global__ void __launch_bounds__(256)
lstm_step(const ushort* __restrict__ w_hi, const ushort* __restrict__ w_lo,   // [2][32][64][512]
          const ushort* __restrict__ hin_hi, const ushort* __restrict__ hin_lo, // [2][128][512]
          ushort* __restrict__ hout_hi, ushort* __restrict__ hout_lo,
          const float* __restrict__ xf, const float* __restrict__ xb,  // xproj per dir [B*T, 2048]
          float* __restrict__ cst,    // [2][128][512]
          float* __restrict__ out,    // [B,T,1024]
          int t)
{
    __shared__ float zbuf[128][65];
    const int tid = threadIdx.x;
    const int dir = blockIdx.x >> 5;
    const int jg  = blockIdx.x & 31;
    const int wave = tid >> 6, lane = tid & 63;
    const int quad = lane >> 4, l16 = lane & 15;

    const ushort* wh = w_hi + ((size_t)dir * 32 + jg) * 64 * 512;
    const ushort* wl = w_lo + ((size_t)dir * 32 + jg) * 64 * 512;
    const ushort* hh = hin_hi + (size_t)dir * 65536;
    const ushort* hl = hin_lo + (size_t)dir * 65536;

    f32x4 acc[2][4];
#pragma unroll
    for (int mt = 0; mt < 2; ++mt)
#pragma unroll
        for (int nt = 0; nt < 4; ++nt)
            acc[mt][nt] = (f32x4){0.f, 0.f, 0.f, 0.f};

    const int m0 = wave * 32 + l16;
#pragma unroll 4
    for (int c = 0; c < 16; ++c) {
        const int k = c * 32 + quad * 8;
        bf16x8 a0h = *(const bf16x8*)&hh[(size_t)m0 * 512 + k];
        bf16x8 a1h = *(const bf16x8*)&hh[(size_t)(m0 + 16) * 512 + k];
        bf16x8 a0l = *(const bf16x8*)&hl[(size_t)m0 * 512 + k];
        bf16x8 a1l = *(const bf16x8*)&hl[(size_t)(m0 + 16) * 512 + k];
#pragma unroll
        for (int nt = 0; nt < 4; ++nt) {
            bf16x8 bh = *(const bf16x8*)&wh[(size_t)(nt * 16 + l16) * 512 + k];
            bf16x8 bl = *(const bf16x8*)&wl[(size_t)(nt * 16 + l16) * 512 + k];
            acc[0][nt] = __builtin_amdgcn_mfma_f32_16x16x32_bf16(a0h, bh, acc[0][nt], 0, 0, 0);
            acc[0][nt] = __builtin_amdgcn_mfma_f32_16x16x32_bf16(a0h, bl, acc[0][nt], 0, 0, 0);
            acc[0][nt] = __builtin_amdgcn_mfma_f32_16x16x32_bf16(a0l, bh, acc[0][nt], 0, 0, 0);
            acc[1][nt] = __builtin_amdgcn_mfma_f32_16x16x32_bf16(a1h, bh, acc[1][nt], 0, 0, 0);
            acc[1][nt] = __builtin_amdgcn_mfma_f32_16x16x32_bf16(a1h, bl, acc[1][nt], 0, 0, 0);
            acc[1][nt] = __builtin_amdgcn_mfma_f32_16x16x32_bf16(a1l, bh, acc[1][nt], 0, 0, 0);
        }
    }

    // C/D layout: col = lane&15 (packed p within tile), row = quad*4 + r
#pragma unroll
    for (int mt = 0; mt < 2; ++mt)
#pragma unroll
        for (int nt = 0; nt < 4; ++nt)
#pragma unroll
            for (int r = 0; r < 4; ++r)
                zbuf[wave * 32 + mt * 16 + quad * 4 + r][nt * 16 + l16] = acc[mt][nt][r];
    __syncthreads();

    // Gate phase: thread -> batch b = tid>>1, 8 j's (jb..jb+7)
    const int b = tid >> 1;
    const int jb = (tid & 1) * 8;
    const int j0 = jg * 16 + jb;
    const int teff = dir ? (255 - t) : t;
    const float* xp = (dir ? xb : xf) + ((size_t)b * 256 + teff) * 2048 + j0;
    float xi[8], xF[8], xg[8], xo[8];
    *(float4*)&xi[0] = *(const float4*)(xp);
    *(float4*)&xi[4] = *(const float4*)(xp + 4);
    *(float4*)&xF[0] = *(const float4*)(xp + 512);
    *(float4*)&xF[4] = *(const float4*)(xp + 516);
    *(float4*)&xg[0] = *(const float4*)(xp + 1024);
    *(float4*)&xg[4] = *(const float4*)(xp + 1028);
    *(float4*)&xo[0] = *(const float4*)(xp + 1536);
    *(float4*)&xo[4] = *(const float4*)(xp + 1540);
    size_t sidx = (size_t)dir * 65536 + (size_t)b * 512 + j0;
    float cv[8], hv[8];
    *(float4*)&cv[0] = *(float4*)&cst[sidx];
    *(float4*)&cv[4] = *(float4*)&cst[sidx + 4];
#pragma unroll
    for (int q = 0; q < 8; ++q) {
        int jj = jb + q;
        float vi = zbuf[b][jj]      + xi[q];
        float vf = zbuf[b][16 + jj] + xF[q];
        float vg = zbuf[b][32 + jj] + xg[q];
        float vo = zbuf[b][48 + jj] + xo[q];
        float is = 1.f / (1.f + expf(-vi));
        float fs = 1.f / (1.f + expf(-vf));
        float gs = tanhf(vg);
        float os = 1.f / (1.f + expf(-vo));
        float c = fs * cv[q] + is * gs;
        cv[q] = c;
        hv[q] = os * tanhf(c);
    }
    *(float4*)&cst[sidx]     = *(float4*)&cv[0];
    *(float4*)&cst[sidx + 4] = *(float4*)&cv[4];

    ushort hhi[8] __attribute__((aligned(16)));
    ushort hlo[8] __attribute__((aligned(16)));
#pragma unroll
    for (int q = 0; q < 8; ++q) {
        ushort hi = f2bf(hv[q]);
        hhi[q] = hi;
        hlo[q] = f2bf(hv[q] - bf2f(hi));
    }
    *(uint4*)&hout_hi[sidx] = *(uint4*)&hhi[0];
    *(uint4*)&hout_lo[sidx] = *(uint4*)&hlo[0];
    float* op = out + ((size_t)b * 256 + teff) * 1024 + (size_t)dir * 512 + j0;
    *(float4*)op       = *(float4*)&hv[0];
    *(float4*)(op + 4) = *(float4*)&hv[4];
}

// ------------------------- attention / classifier tail ---------------------
__global__ void __launch_bounds__(256)
att_score(const float* __restrict__ hidden, const float* __restrict__ aw2,
          const float* __restrict__ ab2, float* __restrict__ scores)
{
    int row = blockIdx.x;
    const float* hrow = hidden + (size_t)row * 1024;
    int tid = threadIdx.x;
    float s = 0.f;
    for (int j = tid; j < 1024; j += 256)
        s += tanhf(hrow[j]) * aw2[j];
    for (int off = 32; off > 0; off >>= 1) s += __shfl_down(s, off);
    __shared__ float red[4];
    if ((tid & 63) == 0) red[tid >> 6] = s;
    __syncthreads();
    if (tid == 0)
        scores[row] = red[0] + red[1] + red[2] + red[3] + ab2[0];
}

__global__ void __launch_bounds__(256)
att_softmax(float* __restrict__ scores, float* __restrict__ attw_out)
{
    int b = blockIdx.x, t = threadIdx.x;
    float v = scores[b * 256 + t];
    __shared__ float red[4];
    float m = v;
    for (int off = 32; off > 0; off >>= 1) m = fmaxf(m, __shfl_down(m, off));
    if ((t & 63) == 0) red[t >> 6] = m;
    __syncthreads();
    float bmax = fmaxf(fmaxf(red[0], red[1]), fmaxf(red[2], red[3]));
    __syncthreads();
    float e = expf(v - bmax);
    float s = e;
    for (int off = 32; off > 0; off >>= 1) s += __shfl_down(s, off);
    if ((t & 63) == 0) red[t >> 6] = s;
    __syncthreads();
    float bsum = red[0] + red[1] + red[2] + red[3];
    float w = e / bsum;
    scores[b * 256 + t] = w;
    attw_out[b * 256 + t] = w;
}

__global__ void __launch_bounds__(256)
att_context(const float* __restrict__ attw, const float* __restrict__ lout,
            float* __restrict__ ctx)
{
    int b = blockIdx.y;
    int j = blockIdx.x * 256 + threadIdx.x;
    float s = 0.f;
    for (int t = 0; t < 256; ++t)
        s += attw[b * 256 + t] * lout[((size_t)b * 256 + t) * 1024 + j];
    ctx[(size_t)b * 1024 + j] = s;
}

__global__ void __launch_bounds__(256)
fc1_kernel(const float* __restrict__ ctx, const float* __restrict__ cw1,
           const float* __restrict__ cb1, float* __restrict__ hid2)
{
    int idx = blockIdx.x * 256 + threadIdx.x;
    int b = idx >> 9, n = idx & 511;
    float s = cb1[n];
    const float* cr = ctx + (size_t)b * 1024;
    for (int k = 0; k < 1024; ++k)
        s = fmaf(cr[k], cw1[(size_t)k * 512 + n], s);
    hid2[idx] = fmaxf(s, 0.f);
}

__global__ void __launch_bounds__(256)
fc2_kernel(const float* __restrict__ hid2, const float* __restrict__ cw2,
           const float* __restrict__ cb2, float* __restrict__ logits)
{
    int idx = blockIdx.x * 256 + threadIdx.x;
    if (idx >= 12800) return;
    int b = idx / 100, n = idx % 100;
    float s = cb2[n];
    const float* hr = hid2 + (size_t)b * 512;
    for (int k = 0; k < 512; ++k)
        s = fmaf(hr[k], cw2[(size_t)k * 100 + n], s);
    logits[idx] = s;
}

extern "C" void kernel_launch(void* const* d_in, const int* in_sizes, int n_in,
                              void* d_out, int out_size, void* d_ws, size_t ws_size,
                              hipStream_t stream)
{
    const float* x        = (const float*)d_in[0];
    const float* w_ih_l0f = (const float*)d_in[1];
    const float* w_hh_l0f = (const float*)d_in[2];
    const float* b_l0f    = (const float*)d_in[3];
    const float* w_ih_l0b = (const float*)d_in[4];
    const float* w_hh_l0b = (const float*)d_in[5];
    const float* b_l0b    = (const float*)d_in[6];
    const float* w_ih_l1f = (const float*)d_in[7];
    const float* w_hh_l1f = (const float*)d_in[8];
    const float* b_l1f    = (const float*)d_in[9];
    const float* w_ih_l1b = (const float*)d_in[10];
    const float* w_hh_l1b = (const float*)d_in[11];
    const float* b_l1b    = (const float*)d_in[12];
    const float* aw1      = (const float*)d_in[13];
    const float* ab1      = (const float*)d_in[14];
    const float* aw2      = (const float*)d_in[15];
    const float* ab2      = (const float*)d_in[16];
    const float* cw1      = (const float*)d_in[17];
    const float* cb1      = (const float*)d_in[18];
    const float* cw2      = (const float*)d_in[19];
    const float* cb2      = (const float*)d_in[20];

    float* ws   = (float*)d_ws;
    float* bufA = ws;                      // 67,108,864 floats  (xproj fwd / att hidden)
    float* bufB = bufA + 67108864;         // 67,108,864         (xproj bwd / aw1^T)
    float* h0   = bufB + 67108864;         // 33,554,432  layer0 out [B,T,1024]
    float* lout = h0   + 33554432;         // 33,554,432  layer1 out
    float* cst  = lout + 33554432;         // 131,072     c state [2][128][512]
    float* scores = cst + 131072;          // 32,768
    float* ctx  = scores + 32768;          // 131,072
    float* hid2 = ctx  + 131072;           // 65,536
    // h ping-pong split-bf16 planes: 4 x 131072 ushorts = 262144 floats
    float* hbase = hid2 + 65536;
    ushort* hA_hi = (ushort*)hbase;
    ushort* hA_lo = hA_hi + 131072;
    ushort* hB_hi = hA_lo + 131072;
    ushort* hB_lo = hB_hi + 131072;
    // packed w_hh split-bf16: per layer [2][32][64][512] hi + lo
    float* wbase = hbase + 262144;
    ushort* w0_hi = (ushort*)wbase;        // 2,097,152 ushorts
    ushort* w0_lo = w0_hi + 2097152;
    ushort* w1_hi = w0_lo + 2097152;
    ushort* w1_lo = w1_hi + 2097152;       // total wbase: 4,194,304 floats

    float* logits   = (float*)d_out;
    float* attw_out = logits + 12800;

    dim3 blk(256);
    const size_t dstride = 32 * 64 * 512;  // per-dir stride in packed weights

    // ---- Pack recurrent weights (once per call) ----
    pack_whh<<<2048, blk, 0, stream>>>(w_hh_l0f, w0_hi, w0_lo);
    pack_whh<<<2048, blk, 0, stream>>>(w_hh_l0b, w0_hi + dstride, w0_lo + dstride);
    pack_whh<<<2048, blk, 0, stream>>>(w_hh_l1f, w1_hi, w1_lo);
    pack_whh<<<2048, blk, 0, stream>>>(w_hh_l1b, w1_hi + dstride, w1_lo + dstride);

    // ---- Layer 0 input projections ----
    gemm_mfma_bt<<<dim3(16, 256), blk, 0, stream>>>(x, 1662, w_ih_l0f, 1662, b_l0f, bufA, 2048L, 1662);
    gemm_mfma_bt<<<dim3(16, 256), blk, 0, stream>>>(x, 1662, w_ih_l0b, 1662, b_l0b, bufB, 2048L, 1662);

    // ---- Layer 0 recurrence: 256 fused steps ----
    hipMemsetAsync(hA_hi, 0, 4 * 131072 * sizeof(ushort), stream); // both ping-pong hi+lo (only A needed)
    hipMemsetAsync(cst, 0, 131072 * sizeof(float), stream);
    for (int t = 0; t < 256; ++t) {
        const ushort* ih = (t & 1) ? hB_hi : hA_hi;
        const ushort* il = (t & 1) ? hB_lo : hA_lo;
        ushort* oh = (t & 1) ? hA_hi : hB_hi;
        ushort* ol = (t & 1) ? hA_lo : hB_lo;
        lstm_step<<<64, blk, 0, stream>>>(w0_hi, w0_lo, ih, il, oh, ol,
                                          bufA, bufB, cst, h0, t);
    }

    // ---- Layer 1 input projections ----
    gemm_mfma_bt<<<dim3(16, 256), blk, 0, stream>>>(h0, 1024, w_ih_l1f, 1024, b_l1f, bufA, 2048L, 1024);
    gemm_mfma_bt<<<dim3(16, 256), blk, 0, stream>>>(h0, 1024, w_ih_l1b, 1024, b_l1b, bufB, 2048L, 1024);

    // ---- Layer 1 recurrence ----
    hipMemsetAsync(hA_hi, 0, 4 * 131072 * sizeof(ushort), stream);
    hipMemsetAsync(cst, 0, 131072 * sizeof(float), stream);
    for (int t = 0; t < 256; ++t) {
        const ushort* ih = (t & 1) ? hB_hi : hA_hi;
        const ushort* il = (t & 1) ? hB_lo : hA_lo;
        ushort* oh = (t & 1) ? hA_hi : hB_hi;
        ushort* ol = (t & 1) ? hA_lo : hB_lo;
        lstm_step<<<64, blk, 0, stream>>>(w1_hi, w1_lo, ih, il, oh, ol,
                                          bufA, bufB, cst, lout, t);
    }

    // ---- Attention ----
    transpose1024<<<dim3(32, 32), blk, 0, stream>>>(aw1, bufB);
    gemm_mfma_bt<<<dim3(8, 256), blk, 0, stream>>>(lout, 1024, bufB, 1024, ab1, bufA, 1024L, 1024);

    att_score<<<32768, blk, 0, stream>>>(bufA, aw2, ab2, scores);
    att_softmax<<<128, blk, 0, stream>>>(scores, attw_out);
    att_context<<<dim3(4, 128), blk, 0, stream>>>(scores, lout, ctx);

    // ---- Classifier ----
    fc1_kernel<<<256, blk, 0, stream>>>(ctx, cw1, cb1, hid2);
    fc2_kernel<<<50, blk, 0, stream>>>(hid2, cw2, cb2, logits);
}